// Round 3
// baseline (234.545 us; speedup 1.0000x reference)
//
#include <hip/hip_runtime.h>
#include <hip/hip_bf16.h>

// out[r][c] = x[r][c] * weight[c] + bias[c]
// x: (8192, 4096) f32, weight/bias: (4096,) f32, out: (8192, 4096) f32.
//
// R1 theory: fixed column-group per thread; w/b loaded ONCE into registers,
// then grid-stride over rows (16 rows/thread). Kills the w/b L2 hot-line
// traffic. Nontemporal stores for out (write-only stream).
// R2 fix: use native clang ext_vector float4 — __builtin_nontemporal_store
// rejects HIP_vector_type wrapper classes.

typedef float f32x4 __attribute__((ext_vector_type(4)));

#define IN_SIZE   4096
#define COLS4     (IN_SIZE / 4)   // 1024 float4 per row
#define BATCH     8192

__global__ __launch_bounds__(256) void diag_linear_kernel(
    const f32x4* __restrict__ x,
    const f32x4* __restrict__ w,
    const f32x4* __restrict__ b,
    f32x4* __restrict__ out)
{
    const int tid        = blockIdx.x * blockDim.x + threadIdx.x; // 0..524287
    const int c4         = tid & (COLS4 - 1);                     // fixed column group
    const int row0       = tid >> 10;                             // 0..511
    const int row_stride = (gridDim.x * blockDim.x) >> 10;        // 512

    // Load diagonal + bias once; reuse across all rows this thread handles.
    const f32x4 wv = w[c4];
    const f32x4 bv = b[c4];

    for (int r = row0; r < BATCH; r += row_stride) {
        const int idx = r * COLS4 + c4;
        f32x4 xv = x[idx];
        f32x4 o = xv * wv + bv;   // vector fma
        __builtin_nontemporal_store(o, &out[idx]);
    }
}

extern "C" void kernel_launch(void* const* d_in, const int* in_sizes, int n_in,
                              void* d_out, int out_size, void* d_ws, size_t ws_size,
                              hipStream_t stream) {
    const f32x4* x = (const f32x4*)d_in[0];
    const f32x4* w = (const f32x4*)d_in[1];
    const f32x4* b = (const f32x4*)d_in[2];
    f32x4* out = (f32x4*)d_out;

    // 2048 blocks x 256 threads = 524288 threads = 1024 col-groups x 512 row-slots.
    // 8 blocks/CU on 256 CUs; each thread loops 16 rows.
    diag_linear_kernel<<<2048, 256, 0, stream>>>(x, w, b, out);
}

// Round 4
// 229.366 us; speedup vs baseline: 1.0226x; 1.0226x over previous
//
#include <hip/hip_runtime.h>
#include <hip/hip_bf16.h>

// out[r][c] = x[r][c] * weight[c] + bias[c]
// x: (8192, 4096) f32, weight/bias: (4096,) f32, out: (8192, 4096) f32.
//
// R3 post-mortem: loop version compiled to VGPR=12 → ONE load in flight per
// wave → latency-bound at 2.5 TB/s. Fix: explicit 8-way unroll, phase-split
// (8 loads issued back-to-back, then 8 fma+store) → 8 KB load MLP per wave.

typedef float f32x4 __attribute__((ext_vector_type(4)));

#define IN_SIZE   4096
#define COLS4     (IN_SIZE / 4)   // 1024 float4 per row
#define BATCH     8192
#define ROWS_PER_THREAD 8

__global__ __launch_bounds__(256) void diag_linear_kernel(
    const f32x4* __restrict__ x,
    const f32x4* __restrict__ w,
    const f32x4* __restrict__ b,
    f32x4* __restrict__ out)
{
    const int tid = blockIdx.x * blockDim.x + threadIdx.x;   // 0..1048575
    const int c4  = tid & (COLS4 - 1);                       // column group
    const int rg  = tid >> 10;                               // row group 0..1023
    const int r0  = rg * ROWS_PER_THREAD;

    const f32x4 wv = w[c4];
    const f32x4 bv = b[c4];

    const f32x4* xp = x + (size_t)r0 * COLS4 + c4;

    // Phase 1: issue all loads (8 outstanding global_load_dwordx4 per lane).
    f32x4 xv[ROWS_PER_THREAD];
#pragma unroll
    for (int i = 0; i < ROWS_PER_THREAD; ++i) {
        xv[i] = xp[(size_t)i * COLS4];
    }

    // Phase 2: compute + store.
    f32x4* op = out + (size_t)r0 * COLS4 + c4;
#pragma unroll
    for (int i = 0; i < ROWS_PER_THREAD; ++i) {
        f32x4 o = xv[i] * wv + bv;
        __builtin_nontemporal_store(o, &op[(size_t)i * COLS4]);
    }
}

extern "C" void kernel_launch(void* const* d_in, const int* in_sizes, int n_in,
                              void* d_out, int out_size, void* d_ws, size_t ws_size,
                              hipStream_t stream) {
    const f32x4* x = (const f32x4*)d_in[0];
    const f32x4* w = (const f32x4*)d_in[1];
    const f32x4* b = (const f32x4*)d_in[2];
    f32x4* out = (f32x4*)d_out;

    // 1024 col-groups x 1024 row-groups (8 rows each) = 1,048,576 threads.
    // 4096 blocks x 256; VGPR ~50 keeps full 32-wave/CU occupancy.
    diag_linear_kernel<<<4096, 256, 0, stream>>>(x, w, b, out);
}